// Round 7
// baseline (230.650 us; speedup 1.0000x reference)
//
#include <hip/hip_runtime.h>

typedef float v2f __attribute__((ext_vector_type(2)));

#define NT 256   // threads per block
#define NR 16    // v2f amplitudes per thread (4-bit register window)

// ---------------------------------------------------------------------------
// LDS swizzle: l ^ ((l>>5)&31) -- measured ~free (2-way max) on all maps.
__device__ __forceinline__ int swz(int l) { return l ^ ((l >> 5) & 31); }

// bf16 pack/unpack (RNE): intermediate state compression.
__device__ __forceinline__ unsigned f2bf(float f) {
  unsigned u = __float_as_uint(f);
  return (u + 0x7fffu + ((u >> 16) & 1u)) >> 16;
}
__device__ __forceinline__ unsigned pack_bf(v2f a) {
  return f2bf(a[0]) | (f2bf(a[1]) << 16);
}
__device__ __forceinline__ v2f unpack_bf(unsigned u) {
  v2f r;
  r[0] = __uint_as_float(u << 16);
  r[1] = __uint_as_float(u & 0xffff0000u);
  return r;
}

// SU(2) rotation on a register pair: U = [[a, b], [-conj(b), conj(a)]]
__device__ __forceinline__ void rot2(v2f& x, v2f& y, v2f aa, v2f an, v2f bb, v2f bn) {
  v2f xs = __builtin_shufflevector(x, x, 1, 0);
  v2f ys = __builtin_shufflevector(y, y, 1, 0);
  v2f n0 = aa * x + an * xs + bb * y + bn * ys;
  v2f n1 = aa * y - an * ys + bn * xs - bb * x;
  x = n0;
  y = n1;
}

#define ROT(T, G)                                                              \
  do {                                                                         \
    const float4 u = Utab[G];                                                  \
    const v2f aa = {u.x, u.x}, an = {-u.y, u.y};                               \
    const v2f bb = {u.z, u.z}, bn = {-u.w, u.w};                               \
    _Pragma("unroll") for (int v = 0; v < NR; ++v) if (!((v >> (T)) & 1))      \
        rot2(s[v], s[v | (1 << (T))], aa, an, bb, bn);                         \
  } while (0)

// CNOT (control C, target T reg-bits): compile-time register swap.
#define CNOTW(C, T)                                                            \
  do {                                                                         \
    _Pragma("unroll") for (int v = 0; v < NR; ++v)                             \
        if (((v >> (C)) & 1) && !((v >> (T)) & 1)) {                           \
      v2f tmp = s[v];                                                          \
      s[v] = s[v | (1 << (T))];                                                \
      s[v | (1 << (T))] = tmp;                                                 \
    }                                                                          \
  } while (0)

// Window maps: 12-bit local index c from (t[7:0], reg v[3:0]).
// Wave bits c11..10 = t7..6 for W2,W3,W4,B3,C4,D63 (wave-local);
// only W1 (c11..8 = v) crosses waves.
#define MAP_W1(t, v)  (((v) << 8) | (t))                               // reg = c11..8
#define MAP_W2(t, v)  ((((t) >> 5) << 9) | ((v) << 5) | ((t) & 31))    // reg = c8..5
#define MAP_W3(t, v)  ((((t) >> 2) << 6) | ((v) << 2) | ((t) & 3))     // reg = c5..2
#define MAP_W4(t, v)  (((t) << 4) | (v))                               // reg = c3..0
#define MAP_B3(t, v)  ((((t) >> 1) << 5) | ((v) << 1) | ((t) & 1))     // reg = c4..1
#define MAP_C4(t, v)  ((((t) >> 4) << 8) | ((v) << 4) | ((t) & 15))    // reg = c7..4
#define MAP_D63(t, v) ((((t) >> 3) << 7) | ((v) << 3) | ((t) & 7))     // reg = c6..3

#define REMAP_W(MW)                                                            \
  _Pragma("unroll") for (int r = 0; r < NR; ++r) lds2[swz(MW(tid, r))] = s[r]
#define REMAP_R(MR)                                                            \
  _Pragma("unroll") for (int v = 0; v < NR; ++v) s[v] = lds2[swz(MR(tid, v))]

// Wave-local remap: no barriers (per-wave in-order DS + compiler lgkmcnt).
#define REMAP_L(MW, MR)  do { REMAP_W(MW); REMAP_R(MR); } while (0)
// Cross-wave write (W1): barrier both sides.
#define REMAP_BWB(MW, MR) do { __syncthreads(); REMAP_W(MW); __syncthreads(); REMAP_R(MR); } while (0)
// Own-region write, barrier, cross-wave read (-> W1).
#define REMAP_WB(MW, MR)  do { REMAP_W(MW); __syncthreads(); REMAP_R(MR); } while (0)

// ---------------------------------------------------------------------------
// Fused U = RZ @ RY @ RX per (layer, wire): (alpha_re, alpha_im, beta_re, beta_im)
__global__ void k_setup(const float* __restrict__ params, float4* __restrict__ Utab) {
  int g = threadIdx.x;
  if (g < 64) {
    float a = params[g * 3 + 0] * 0.5f;
    float b = params[g * 3 + 1] * 0.5f;
    float c = params[g * 3 + 2] * 0.5f;
    float sa, ca, sb, cb, sc, cc;
    sincosf(a, &sa, &ca);
    sincosf(b, &sb, &cb);
    sincosf(c, &sc, &cc);
    float X = cb * ca, Y = sb * sa;
    float Xp = -sb * ca, Yp = -cb * sa;
    Utab[g] = make_float4(cc * X + sc * Y, cc * Y - sc * X,
                          cc * Xp + sc * Yp, cc * Yp - sc * Xp);
  }
}

// ---------------------------------------------------------------------------
// Pass A: local wires 0..11 (orig bits 15..4); wire q <-> local bit 11-q.
// Executes R_l(q <= 11-l), C_l(q,q+1) for q <= 10-l (staircase light-cone).
// Tile 4096 amps = 32 KB LDS; g = orig bits 3..0 (16 chunks/batch).
__global__ __launch_bounds__(NT, 5) void k_passA(const float* __restrict__ in,
                                                 const float4* __restrict__ Utab,
                                                 unsigned* __restrict__ st) {
  __shared__ v2f lds2[4096];
  const int tid = threadIdx.x;
  // XCD grouping: all 16 g-siblings of batch b on one XCD, adjacent slots.
  const int xcd = blockIdx.x & 7;
  const int y = blockIdx.x >> 3;
  const int g = y & 15;
  const int b = xcd | ((y >> 4) << 3);
  const float* base = in + (size_t)b * 65536;

  v2f s[NR];
  // Direct load in W1 arrangement: orig = v<<12 | tid<<4 | g.
#pragma unroll
  for (int v = 0; v < NR; ++v) {
    float re = base[(v << 12) + (tid << 4) + g];
    s[v] = v2f{re, 0.0f};
  }

#pragma unroll
  for (int l = 0; l < 4; ++l) {
    // W1: reg c11..8 = wires 0..3 (T = 3-q)
    ROT(3, l * 16 + 0); ROT(2, l * 16 + 1); ROT(1, l * 16 + 2); ROT(0, l * 16 + 3);
    CNOTW(3, 2); CNOTW(2, 1); CNOTW(1, 0);       // C_l (0,1),(1,2),(2,3)
    REMAP_BWB(MAP_W1, MAP_W2);
    // W2: reg c8..5 = wires 3..6; rotations on 4,5,6 (T = 6-q)
    ROT(2, l * 16 + 4); ROT(1, l * 16 + 5); ROT(0, l * 16 + 6);
    CNOTW(3, 2); CNOTW(2, 1); CNOTW(1, 0);       // C_l (3,4),(4,5),(5,6)
    REMAP_L(MAP_W2, MAP_W3);
    // W3: reg c5..2 = wires 6..9 (T = 9-q); staircase trims l=2,3
    ROT(2, l * 16 + 7); ROT(1, l * 16 + 8);
    if (l <= 2) ROT(0, l * 16 + 9);
    CNOTW(3, 2); CNOTW(2, 1);                    // C_l (6,7),(7,8)
    if (l <= 2) CNOTW(1, 0);                     // C_l (8,9)
    if (l <= 1) {
      REMAP_L(MAP_W3, MAP_W4);
      // W4: reg c3..0 = wires 8..11 (T = 11-q); staircase tail
      if (l == 0) { ROT(1, 10); ROT(0, 11); CNOTW(2, 1); CNOTW(1, 0); }
      else        { ROT(1, 16 + 10); CNOTW(2, 1); }
      REMAP_WB(MAP_W4, MAP_W1);
    } else if (l == 2) {
      REMAP_WB(MAP_W3, MAP_W1);
    }
  }

  // Exit (arrangement W3): own-region write, barrier, linear coalesced
  // bf16-packed stores. Chunk layout: st[(b*16+g)*4096 + m], amp orig = m<<4|g.
  REMAP_W(MAP_W3);
  __syncthreads();
  unsigned* outp = st + (size_t)(b * 16 + g) * 4096;
#pragma unroll
  for (int k = 0; k < 16; ++k)
    outp[(k << 8) + tid] = pack_bf(lds2[swz((k << 8) | tid)]);
}

// ---------------------------------------------------------------------------
// Pass B: local wires 4..15 (orig bits 11..0); wire q <-> local bit 15-q.
// Executes remaining staircase ops (active bits 7..0 only). All remaps
// wave-local -> barrier-free. h = orig bits 15..12 (16 blocks/batch).
__global__ __launch_bounds__(NT, 5) void k_passB(const unsigned* __restrict__ st,
                                                 const float4* __restrict__ Utab,
                                                 float* __restrict__ partials) {
  __shared__ v2f lds2[4096];
  const int tid = threadIdx.x;
  const int b = blockIdx.x >> 4;
  const int h = blockIdx.x & 15;
  const unsigned* base = st + (size_t)b * 65536;

  // Direct coalesced entry in W4 arrangement: amp c = tid<<4 | v lives in
  // chunk g = v at row h<<8 | tid (bf16-packed, mostly L3-resident).
  v2f s[NR];
#pragma unroll
  for (int v = 0; v < NR; ++v)
    s[v] = unpack_bf(base[(size_t)v * 4096 + (h << 8) + tid]);

  // pre (W4, bits 3..0): R0 wires 12..15 (T = 15-q)
  ROT(3, 12); ROT(2, 13); ROT(1, 14); ROT(0, 15);
  REMAP_L(MAP_W4, MAP_B3);
  // Q0 (bits 4..1, T = bit-1): C0 chain head + R1 high
  CNOTW(3, 2); CNOTW(2, 1); CNOTW(1, 0);        // C0 (11,12),(12,13),(13,14)
  ROT(3, 16 + 11); ROT(2, 16 + 12); ROT(1, 16 + 13);  // R1 w11,12,13
  REMAP_L(MAP_B3, MAP_W4);
  // Q1 (bits 3..0): chain tails
  CNOTW(1, 0);                                   // C0 (14,15)
  ROT(1, 16 + 14); ROT(0, 16 + 15);              // R1 w14,15
  REMAP_L(MAP_W4, MAP_C4);
  // D0 (bits 7..4, T = bit-4)
  CNOTW(1, 0);                                   // C1 (10,11)
  ROT(1, 32 + 10);                               // R2 w10
  CNOTW(2, 1);                                   // C2 (9,10)
  ROT(2, 48 + 9);                                // R3 w9
  CNOTW(3, 2);                                   // C3 (8,9)
  REMAP_L(MAP_C4, MAP_D63);
  // D1 (bits 6..3, T = bit-3)
  CNOTW(1, 0);                                   // C1 (11,12)
  ROT(1, 32 + 11);                               // R2 w11
  CNOTW(2, 1);                                   // C2 (10,11)
  ROT(2, 48 + 10);                               // R3 w10
  CNOTW(3, 2);                                   // C3 (9,10)
  REMAP_L(MAP_D63, MAP_W3);
  // D2 (bits 5..2, T = bit-2)
  CNOTW(1, 0);                                   // C1 (12,13)
  ROT(1, 32 + 12);                               // R2 w12
  CNOTW(2, 1);                                   // C2 (11,12)
  ROT(2, 48 + 11);                               // R3 w11
  CNOTW(3, 2);                                   // C3 (10,11)
  REMAP_L(MAP_W3, MAP_B3);
  // D3 (bits 4..1, T = bit-1)
  CNOTW(1, 0);                                   // C1 (13,14)
  ROT(1, 32 + 13);                               // R2 w13
  CNOTW(2, 1);                                   // C2 (12,13)
  ROT(2, 48 + 12);                               // R3 w12
  CNOTW(3, 2);                                   // C3 (11,12)
  REMAP_L(MAP_B3, MAP_W4);
  // D4 (bits 3..0): chain tails
  CNOTW(1, 0);                                   // C1 (14,15)
  ROT(1, 32 + 14); ROT(0, 32 + 15);              // R2 w14,15
  CNOTW(2, 1); CNOTW(1, 0);                      // C2 (13,14),(14,15)
  ROT(2, 48 + 13); ROT(1, 48 + 14); ROT(0, 48 + 15);  // R3 w13,14,15
  CNOTW(3, 2); CNOTW(2, 1); CNOTW(1, 0);         // C3 (12,13),(13,14),(14,15)

  // Epilogue (W4 arrangement): c = t<<4|v; wires 12..15 <-> v3..0,
  // wires 4..11 <-> t7..0 (wire q <-> t bit 11-q), wires 0..3 <-> h bits 3..0.
  float P = 0.f, f12 = 0.f, f13 = 0.f, f14 = 0.f, f15 = 0.f;
#pragma unroll
  for (int v = 0; v < NR; ++v) {
    float p = s[v][0] * s[v][0] + s[v][1] * s[v][1];
    P += p;
    f12 += ((v >> 3) & 1) ? -p : p;
    f13 += ((v >> 2) & 1) ? -p : p;
    f14 += ((v >> 1) & 1) ? -p : p;
    f15 += ((v >> 0) & 1) ? -p : p;
  }
  float vals[13];
  vals[0] = P;
#pragma unroll
  for (int q = 4; q <= 11; ++q)
    vals[q - 3] = ((tid >> (11 - q)) & 1) ? -P : P;
  vals[9] = f12; vals[10] = f13; vals[11] = f14; vals[12] = f15;

  const int lane = tid & 63, w = tid >> 6;
#pragma unroll
  for (int q = 0; q < 13; ++q) {
    float x = vals[q];
#pragma unroll
    for (int m = 1; m < 64; m <<= 1) x += __shfl_xor(x, m, 64);
    vals[q] = x;
  }
  __syncthreads();  // red[] lives in wave-0's region
  float* red = (float*)lds2;
  if (lane == 0) {
#pragma unroll
    for (int q = 0; q < 13; ++q) red[q * 4 + w] = vals[q];
  }
  __syncthreads();
  if (tid < 13) {
    float F = 0.f;
#pragma unroll
    for (int ww = 0; ww < 4; ++ww) F += red[tid * 4 + ww];
    float* pt = partials + (size_t)blockIdx.x * 16;
    if (tid == 0) {
      pt[0] = (h & 8) ? -F : F;  // wire 0 <-> h bit 3
      pt[1] = (h & 4) ? -F : F;  // wire 1
      pt[2] = (h & 2) ? -F : F;  // wire 2
      pt[3] = (h & 1) ? -F : F;  // wire 3
    } else {
      pt[tid + 3] = F;           // tid 1..8 -> wires 4..11; 9..12 -> 12..15
    }
  }
}

// ---------------------------------------------------------------------------
__global__ void k_head(const float* __restrict__ partials, const float* __restrict__ w,
                       const float* __restrict__ bh, float* __restrict__ out) {
  int b = threadIdx.x;  // 256 threads
  float acc = bh[0];
  for (int q = 0; q < 16; ++q) {
    float F = 0.f;
    for (int hh = 0; hh < 16; ++hh) F += partials[(size_t)(b * 16 + hh) * 16 + q];
    acc += w[q] * F;
  }
  out[b] = acc;
}

// ---------------------------------------------------------------------------
extern "C" void kernel_launch(void* const* d_in, const int* in_sizes, int n_in,
                              void* d_out, int out_size, void* d_ws, size_t ws_size,
                              hipStream_t stream) {
  const float* state  = (const float*)d_in[0];
  const float* params = (const float*)d_in[1];
  const float* w_head = (const float*)d_in[2];
  const float* b_head = (const float*)d_in[3];
  float* out = (float*)d_out;

  char* ws = (char*)d_ws;
  unsigned* st = (unsigned*)ws;                             // 64 MB (bf16 pairs)
  float4* Utab = (float4*)(ws + (size_t)67108864);          // 1 KB
  float* partials = (float*)(ws + (size_t)67108864 + 1024); // 256 KB

  k_setup<<<1, 64, 0, stream>>>(params, Utab);
  k_passA<<<dim3(4096), dim3(NT), 0, stream>>>(state, Utab, st);
  k_passB<<<dim3(4096), dim3(NT), 0, stream>>>(st, Utab, partials);
  k_head<<<1, 256, 0, stream>>>(partials, w_head, b_head, out);
}

// Round 8
// 222.112 us; speedup vs baseline: 1.0384x; 1.0384x over previous
//
#include <hip/hip_runtime.h>

typedef float v2f __attribute__((ext_vector_type(2)));

#define NT 256   // threads per block
#define NR 16    // v2f amplitudes per thread (4-bit register window)

// ---------------------------------------------------------------------------
// LDS swizzle: l ^ ((l>>5)&31) -- measured ~free (2-way max) on all maps.
__device__ __forceinline__ int swz(int l) { return l ^ ((l >> 5) & 31); }

// SU(2) rotation on a register pair: U = [[a, b], [-conj(b), conj(a)]]
__device__ __forceinline__ void rot2(v2f& x, v2f& y, v2f aa, v2f an, v2f bb, v2f bn) {
  v2f xs = __builtin_shufflevector(x, x, 1, 0);
  v2f ys = __builtin_shufflevector(y, y, 1, 0);
  v2f n0 = aa * x + an * xs + bb * y + bn * ys;
  v2f n1 = aa * y - an * ys + bn * xs - bb * x;
  x = n0;
  y = n1;
}

#define ROT(T, G)                                                              \
  do {                                                                         \
    const float4 u = Utab[G];                                                  \
    const v2f aa = {u.x, u.x}, an = {-u.y, u.y};                               \
    const v2f bb = {u.z, u.z}, bn = {-u.w, u.w};                               \
    _Pragma("unroll") for (int v = 0; v < NR; ++v) if (!((v >> (T)) & 1))      \
        rot2(s[v], s[v | (1 << (T))], aa, an, bb, bn);                         \
  } while (0)

// CNOT (control C, target T reg-bits): compile-time register swap.
#define CNOTW(C, T)                                                            \
  do {                                                                         \
    _Pragma("unroll") for (int v = 0; v < NR; ++v)                             \
        if (((v >> (C)) & 1) && !((v >> (T)) & 1)) {                           \
      v2f tmp = s[v];                                                          \
      s[v] = s[v | (1 << (T))];                                                \
      s[v | (1 << (T))] = tmp;                                                 \
    }                                                                          \
  } while (0)

// Window maps: 12-bit local index c from (t[7:0], reg v[3:0]).
// Wave bits c11..10 = t7..6 for W2,W3,W4,B3,C4,D63 (wave-local);
// only W1 (c11..8 = v) crosses waves.
#define MAP_W1(t, v)  (((v) << 8) | (t))                               // reg = c11..8
#define MAP_W2(t, v)  ((((t) >> 5) << 9) | ((v) << 5) | ((t) & 31))    // reg = c8..5
#define MAP_W3(t, v)  ((((t) >> 2) << 6) | ((v) << 2) | ((t) & 3))     // reg = c5..2
#define MAP_W4(t, v)  (((t) << 4) | (v))                               // reg = c3..0
#define MAP_B3(t, v)  ((((t) >> 1) << 5) | ((v) << 1) | ((t) & 1))     // reg = c4..1
#define MAP_C4(t, v)  ((((t) >> 4) << 8) | ((v) << 4) | ((t) & 15))    // reg = c7..4
#define MAP_D63(t, v) ((((t) >> 3) << 7) | ((v) << 3) | ((t) & 7))     // reg = c6..3

#define REMAP_W(MW)                                                            \
  _Pragma("unroll") for (int r = 0; r < NR; ++r) lds2[swz(MW(tid, r))] = s[r]
#define REMAP_R(MR)                                                            \
  _Pragma("unroll") for (int v = 0; v < NR; ++v) s[v] = lds2[swz(MR(tid, v))]

// Wave-local remap: no barriers (per-wave in-order DS + compiler lgkmcnt).
#define REMAP_L(MW, MR)  do { REMAP_W(MW); REMAP_R(MR); } while (0)
// Cross-wave write (W1): barrier both sides.
#define REMAP_BWB(MW, MR) do { __syncthreads(); REMAP_W(MW); __syncthreads(); REMAP_R(MR); } while (0)
// Own-region write, barrier, cross-wave read (-> W1).
#define REMAP_WB(MW, MR)  do { REMAP_W(MW); __syncthreads(); REMAP_R(MR); } while (0)

// ---------------------------------------------------------------------------
// Fused U = RZ @ RY @ RX per (layer, wire): (alpha_re, alpha_im, beta_re, beta_im)
__global__ void k_setup(const float* __restrict__ params, float4* __restrict__ Utab) {
  int g = threadIdx.x;
  if (g < 64) {
    float a = params[g * 3 + 0] * 0.5f;
    float b = params[g * 3 + 1] * 0.5f;
    float c = params[g * 3 + 2] * 0.5f;
    float sa, ca, sb, cb, sc, cc;
    sincosf(a, &sa, &ca);
    sincosf(b, &sb, &cb);
    sincosf(c, &sc, &cc);
    float X = cb * ca, Y = sb * sa;
    float Xp = -sb * ca, Yp = -cb * sa;
    Utab[g] = make_float4(cc * X + sc * Y, cc * Y - sc * X,
                          cc * Xp + sc * Yp, cc * Yp - sc * Xp);
  }
}

// ---------------------------------------------------------------------------
// Pass A: local wires 0..11 (orig bits 15..4); wire q <-> local bit 11-q.
// Executes R_l(q <= 11-l), C_l(q,q+1) for q <= 10-l (staircase light-cone).
// Tile 4096 amps = 32 KB LDS; g = orig bits 3..0 (16 chunks/batch).
__global__ __launch_bounds__(NT, 4) void k_passA(const float* __restrict__ in,
                                                 const float4* __restrict__ Utab,
                                                 v2f* __restrict__ st) {
  __shared__ v2f lds2[4096];
  const int tid = threadIdx.x;
  // XCD grouping: all 16 g-siblings of batch b on one XCD, adjacent slots.
  const int xcd = blockIdx.x & 7;
  const int y = blockIdx.x >> 3;
  const int g = y & 15;
  const int b = xcd | ((y >> 4) << 3);
  const float* base = in + (size_t)b * 65536;

  v2f s[NR];
  // Direct load in W1 arrangement: orig = v<<12 | tid<<4 | g.
#pragma unroll
  for (int v = 0; v < NR; ++v) {
    float re = base[(v << 12) + (tid << 4) + g];
    s[v] = v2f{re, 0.0f};
  }

#pragma unroll
  for (int l = 0; l < 4; ++l) {
    // W1: reg c11..8 = wires 0..3 (T = 3-q)
    ROT(3, l * 16 + 0); ROT(2, l * 16 + 1); ROT(1, l * 16 + 2); ROT(0, l * 16 + 3);
    CNOTW(3, 2); CNOTW(2, 1); CNOTW(1, 0);       // C_l (0,1),(1,2),(2,3)
    REMAP_BWB(MAP_W1, MAP_W2);
    // W2: reg c8..5 = wires 3..6; rotations on 4,5,6 (T = 6-q)
    ROT(2, l * 16 + 4); ROT(1, l * 16 + 5); ROT(0, l * 16 + 6);
    CNOTW(3, 2); CNOTW(2, 1); CNOTW(1, 0);       // C_l (3,4),(4,5),(5,6)
    REMAP_L(MAP_W2, MAP_W3);
    // W3: reg c5..2 = wires 6..9 (T = 9-q); staircase trims l=2,3
    ROT(2, l * 16 + 7); ROT(1, l * 16 + 8);
    if (l <= 2) ROT(0, l * 16 + 9);
    CNOTW(3, 2); CNOTW(2, 1);                    // C_l (6,7),(7,8)
    if (l <= 2) CNOTW(1, 0);                     // C_l (8,9)
    if (l <= 1) {
      REMAP_L(MAP_W3, MAP_W4);
      // W4: reg c3..0 = wires 8..11 (T = 11-q); staircase tail
      if (l == 0) { ROT(1, 10); ROT(0, 11); CNOTW(2, 1); CNOTW(1, 0); }
      else        { ROT(1, 16 + 10); CNOTW(2, 1); }
      REMAP_WB(MAP_W4, MAP_W1);
    } else if (l == 2) {
      REMAP_WB(MAP_W3, MAP_W1);
    }
  }

  // Exit (arrangement W3): own-region write, barrier, then stores into the
  // paired-interleave layout st[b][g>>1][m][g&1] (v2f units:
  // b*65536 + (g>>1)*8192 + 2m + (g&1)) so passB reads are float4-coalesced.
  // Sibling g^1 (same XCD/L2, adjacent launch) completes each 16B pair.
  REMAP_W(MAP_W3);
  __syncthreads();
  v2f* outp = st + (size_t)b * 65536 + ((g >> 1) << 13) + (g & 1);
#pragma unroll
  for (int k = 0; k < 16; ++k) {
    int m = (k << 8) | tid;
    outp[m << 1] = lds2[swz((k << 8) | tid)];
  }
}

// ---------------------------------------------------------------------------
// Pass B: local wires 4..15 (orig bits 11..0); wire q <-> local bit 15-q.
// Executes remaining staircase ops (active bits 7..0 only). All remaps
// wave-local -> barrier-free. h = orig bits 15..12 (16 blocks/batch).
__global__ __launch_bounds__(NT, 4) void k_passB(const v2f* __restrict__ st,
                                                 const float4* __restrict__ Utab,
                                                 float* __restrict__ partials) {
  __shared__ v2f lds2[4096];
  const int tid = threadIdx.x;
  const int b = blockIdx.x >> 4;
  const int h = blockIdx.x & 15;
  const float4* base4 = (const float4*)(st + (size_t)b * 65536);

  // Coalesced float4 entry in W4 arrangement: float4 (g2, m) holds chunks
  // g=2g2, 2g2+1 of amp m = h<<8|tid; s[v] = amp (m<<4)|v.
  v2f s[NR];
#pragma unroll
  for (int g2 = 0; g2 < 8; ++g2) {
    float4 f = base4[(g2 << 12) + (h << 8) + tid];
    s[2 * g2]     = v2f{f.x, f.y};
    s[2 * g2 + 1] = v2f{f.z, f.w};
  }

  // pre (W4, bits 3..0): R0 wires 12..15 (T = 15-q)
  ROT(3, 12); ROT(2, 13); ROT(1, 14); ROT(0, 15);
  REMAP_L(MAP_W4, MAP_B3);
  // Q0 (bits 4..1, T = bit-1): C0 chain head + R1 high
  CNOTW(3, 2); CNOTW(2, 1); CNOTW(1, 0);        // C0 (11,12),(12,13),(13,14)
  ROT(3, 16 + 11); ROT(2, 16 + 12); ROT(1, 16 + 13);  // R1 w11,12,13
  REMAP_L(MAP_B3, MAP_W4);
  // Q1 (bits 3..0): chain tails
  CNOTW(1, 0);                                   // C0 (14,15)
  ROT(1, 16 + 14); ROT(0, 16 + 15);              // R1 w14,15
  REMAP_L(MAP_W4, MAP_C4);
  // D0 (bits 7..4, T = bit-4)
  CNOTW(1, 0);                                   // C1 (10,11)
  ROT(1, 32 + 10);                               // R2 w10
  CNOTW(2, 1);                                   // C2 (9,10)
  ROT(2, 48 + 9);                                // R3 w9
  CNOTW(3, 2);                                   // C3 (8,9)
  REMAP_L(MAP_C4, MAP_D63);
  // D1 (bits 6..3, T = bit-3)
  CNOTW(1, 0);                                   // C1 (11,12)
  ROT(1, 32 + 11);                               // R2 w11
  CNOTW(2, 1);                                   // C2 (10,11)
  ROT(2, 48 + 10);                               // R3 w10
  CNOTW(3, 2);                                   // C3 (9,10)
  REMAP_L(MAP_D63, MAP_W3);
  // D2 (bits 5..2, T = bit-2)
  CNOTW(1, 0);                                   // C1 (12,13)
  ROT(1, 32 + 12);                               // R2 w12
  CNOTW(2, 1);                                   // C2 (11,12)
  ROT(2, 48 + 11);                               // R3 w11
  CNOTW(3, 2);                                   // C3 (10,11)
  REMAP_L(MAP_W3, MAP_B3);
  // D3 (bits 4..1, T = bit-1)
  CNOTW(1, 0);                                   // C1 (13,14)
  ROT(1, 32 + 13);                               // R2 w13
  CNOTW(2, 1);                                   // C2 (12,13)
  ROT(2, 48 + 12);                               // R3 w12
  CNOTW(3, 2);                                   // C3 (11,12)
  REMAP_L(MAP_B3, MAP_W4);
  // D4 (bits 3..0): chain tails
  CNOTW(1, 0);                                   // C1 (14,15)
  ROT(1, 32 + 14); ROT(0, 32 + 15);              // R2 w14,15
  CNOTW(2, 1); CNOTW(1, 0);                      // C2 (13,14),(14,15)
  ROT(2, 48 + 13); ROT(1, 48 + 14); ROT(0, 48 + 15);  // R3 w13,14,15
  CNOTW(3, 2); CNOTW(2, 1); CNOTW(1, 0);         // C3 (12,13),(13,14),(14,15)

  // Epilogue (W4 arrangement): c = t<<4|v; wires 12..15 <-> v3..0,
  // wires 4..11 <-> t7..0 (wire q <-> t bit 11-q), wires 0..3 <-> h bits 3..0.
  float P = 0.f, f12 = 0.f, f13 = 0.f, f14 = 0.f, f15 = 0.f;
#pragma unroll
  for (int v = 0; v < NR; ++v) {
    float p = s[v][0] * s[v][0] + s[v][1] * s[v][1];
    P += p;
    f12 += ((v >> 3) & 1) ? -p : p;
    f13 += ((v >> 2) & 1) ? -p : p;
    f14 += ((v >> 1) & 1) ? -p : p;
    f15 += ((v >> 0) & 1) ? -p : p;
  }
  float vals[13];
  vals[0] = P;
#pragma unroll
  for (int q = 4; q <= 11; ++q)
    vals[q - 3] = ((tid >> (11 - q)) & 1) ? -P : P;
  vals[9] = f12; vals[10] = f13; vals[11] = f14; vals[12] = f15;

  const int lane = tid & 63, w = tid >> 6;
#pragma unroll
  for (int q = 0; q < 13; ++q) {
    float x = vals[q];
#pragma unroll
    for (int m = 1; m < 64; m <<= 1) x += __shfl_xor(x, m, 64);
    vals[q] = x;
  }
  __syncthreads();  // red[] lives in wave-0's region
  float* red = (float*)lds2;
  if (lane == 0) {
#pragma unroll
    for (int q = 0; q < 13; ++q) red[q * 4 + w] = vals[q];
  }
  __syncthreads();
  if (tid < 13) {
    float F = 0.f;
#pragma unroll
    for (int ww = 0; ww < 4; ++ww) F += red[tid * 4 + ww];
    float* pt = partials + (size_t)blockIdx.x * 16;
    if (tid == 0) {
      pt[0] = (h & 8) ? -F : F;  // wire 0 <-> h bit 3
      pt[1] = (h & 4) ? -F : F;  // wire 1
      pt[2] = (h & 2) ? -F : F;  // wire 2
      pt[3] = (h & 1) ? -F : F;  // wire 3
    } else {
      pt[tid + 3] = F;           // tid 1..8 -> wires 4..11; 9..12 -> 12..15
    }
  }
}

// ---------------------------------------------------------------------------
__global__ void k_head(const float* __restrict__ partials, const float* __restrict__ w,
                       const float* __restrict__ bh, float* __restrict__ out) {
  int b = threadIdx.x;  // 256 threads
  float acc = bh[0];
  for (int q = 0; q < 16; ++q) {
    float F = 0.f;
    for (int hh = 0; hh < 16; ++hh) F += partials[(size_t)(b * 16 + hh) * 16 + q];
    acc += w[q] * F;
  }
  out[b] = acc;
}

// ---------------------------------------------------------------------------
extern "C" void kernel_launch(void* const* d_in, const int* in_sizes, int n_in,
                              void* d_out, int out_size, void* d_ws, size_t ws_size,
                              hipStream_t stream) {
  const float* state  = (const float*)d_in[0];
  const float* params = (const float*)d_in[1];
  const float* w_head = (const float*)d_in[2];
  const float* b_head = (const float*)d_in[3];
  float* out = (float*)d_out;

  char* ws = (char*)d_ws;
  v2f* st = (v2f*)ws;                                       // 128 MB
  float4* Utab = (float4*)(ws + (size_t)134217728);         // 1 KB
  float* partials = (float*)(ws + (size_t)134217728 + 1024);// 256 KB

  k_setup<<<1, 64, 0, stream>>>(params, Utab);
  k_passA<<<dim3(4096), dim3(NT), 0, stream>>>(state, Utab, st);
  k_passB<<<dim3(4096), dim3(NT), 0, stream>>>(st, Utab, partials);
  k_head<<<1, 256, 0, stream>>>(partials, w_head, b_head, out);
}